// Round 12
// baseline (372.162 us; speedup 1.0000x reference)
//
#include <hip/hip_runtime.h>

#define N_SEQ 2048
#define CDIM 512
#define HEADS 8
#define DH 64
#define WINDOW 64
#define BATCH 2

typedef __attribute__((ext_vector_type(8))) short bf16x8;
typedef __attribute__((ext_vector_type(4))) short short4v;
typedef __attribute__((ext_vector_type(4))) float f32x4;

__device__ __forceinline__ unsigned short f2b(float f){
  unsigned u = __float_as_uint(f);
  unsigned r = (u + 0x7fffu + ((u >> 16) & 1u)) >> 16;
  return (unsigned short)r;
}
__device__ __forceinline__ float b2f(unsigned short h){ return __uint_as_float(((unsigned)h) << 16); }

__device__ __forceinline__ void gl_lds16(const void* g, void* l){
  __builtin_amdgcn_global_load_lds(
      (const __attribute__((address_space(1))) void*)g,
      (__attribute__((address_space(3))) void*)l, 16, 0, 0);
}

// grid-wide barrier: all blocks resident by construction (512 blocks, 2/CU capacity).
__device__ __forceinline__ void grid_barrier(unsigned* ctr, unsigned target){
  __threadfence();                                  // release: each thread flushes its writes
  __syncthreads();
  if (threadIdx.x == 0){
    atomicAdd(ctr, 1u);                             // device-scope by default
    while (__hip_atomic_load(ctr, __ATOMIC_ACQUIRE, __HIP_MEMORY_SCOPE_AGENT) < target)
      __builtin_amdgcn_s_sleep(2);
  }
  __syncthreads();
  __threadfence();                                  // acquire: invalidate stale cache
}

// ================= prep: x->bf16 + fused-weight transposes (W_eff = w + 0.25*lA@lB)
//                   + zero the mega-kernel barrier counters =================
__global__ __launch_bounds__(256) void prep(
    const float* __restrict__ x,
    const float* __restrict__ w_qkv, const float* __restrict__ lA_qkv, const float* __restrict__ lB_qkv,
    const float* __restrict__ w_out, const float* __restrict__ lA_out, const float* __restrict__ lB_out,
    short* __restrict__ A1, short* __restrict__ wT1, short* __restrict__ wT2,
    unsigned* __restrict__ bar){
  const int bx = blockIdx.x, tid = threadIdx.x;
  if (bx < 512){
    #pragma unroll
    for (int j = 0; j < 4; j++){
      int g = bx*1024 + j*256 + tid;          // float4 index over 2M elements
      float4 v = ((const float4*)x)[g];
      short4v pk;
      pk[0] = (short)f2b(v.x); pk[1] = (short)f2b(v.y);
      pk[2] = (short)f2b(v.z); pk[3] = (short)f2b(v.w);
      ((short4v*)A1)[g] = pk;
    }
    return;
  }
  if (bx == 767 && tid < 8) bar[tid] = 0;     // zero barrier counters for mega
  __shared__ float T[64][65];
  __shared__ float lAs[64][9];
  __shared__ float lBs[8][64];
  const float *wsrc, *lA, *lB; short* dst; int NN, ct, kt;
  if (bx < 704){ int bxx = bx - 512; wsrc = w_qkv; lA = lA_qkv; lB = lB_qkv; dst = wT1; NN = 1536; ct = bxx % 24; kt = bxx / 24; }
  else         { int bxx = bx - 704; wsrc = w_out; lA = lA_out; lB = lB_out; dst = wT2; NN = 512;  ct = bxx % 8;  kt = bxx / 8; }
  const int n0 = ct*64, k0 = kt*64;
  {
    int t0 = tid, t1 = tid + 256;
    lAs[t0 >> 3][t0 & 7] = lA[(size_t)(k0 + (t0 >> 3))*8 + (t0 & 7)];
    lAs[t1 >> 3][t1 & 7] = lA[(size_t)(k0 + (t1 >> 3))*8 + (t1 & 7)];
    lBs[t0 >> 6][t0 & 63] = lB[(size_t)(t0 >> 6)*NN + n0 + (t0 & 63)];
    lBs[4 + (t0 >> 6)][t0 & 63] = lB[(size_t)(4 + (t0 >> 6))*NN + n0 + (t0 & 63)];
  }
  #pragma unroll
  for (int it = 0; it < 16; it++){
    int r = (tid >> 6) + it*4, c = tid & 63;
    T[r][c] = wsrc[(size_t)(k0 + r)*NN + n0 + c];
  }
  __syncthreads();
  #pragma unroll
  for (int it = 0; it < 16; it++){
    int rw = (tid >> 6) + it*4, cw = tid & 63;   // out n = n0+rw, k = k0+cw
    float lora = 0.f;
    #pragma unroll
    for (int r = 0; r < 8; r++) lora += lAs[cw][r] * lBs[r][rw];
    dst[(size_t)(n0 + rw)*512 + k0 + cw] = (short)f2b(T[cw][rw] + 0.25f*lora);
  }
}

// ================= mega: qkv GEMM | attn | out GEMM with 2 grid barriers =================
__global__ void __launch_bounds__(256, 2) mega(
    const short* __restrict__ A1, const short* __restrict__ wT1,
    const short* __restrict__ wT2, const float* __restrict__ bias,
    short* __restrict__ qb, short* __restrict__ kb,
    short* __restrict__ vT, short* __restrict__ vgT,
    short* __restrict__ A2, float* __restrict__ outp,
    unsigned* __restrict__ bar){
  __shared__ __align__(16) char RAW[49152];
  const int tid = threadIdx.x;
  const int bid = blockIdx.x;
  const int wid = tid >> 6, lane = tid & 63;
  const int ln = lane & 15, lg = lane >> 4;

  // ---------------- phase 1: qkv GEMM (384 of 512 blocks; R10 body) ----------------
  if (bid < 384){
    short* AsB = (short*)RAW;
    short* BsB = (short*)RAW + 12288;
    const int s = (bid & 7)*48 + (bid >> 3);            // XCD swizzle (384%8==0)
    const int m0 = (s/12)*128, n0 = (s%12)*128;
    const int wr = wid >> 1, wc = wid & 1;              // FM=FN=4
    f32x4 acc[4][4];
    #pragma unroll
    for (int mi = 0; mi < 4; mi++)
      #pragma unroll
      for (int ni = 0; ni < 4; ni++){ f32x4 z = {0.f,0.f,0.f,0.f}; acc[mi][ni] = z; }

    auto stage = [&](int k0, int buf){
      #pragma unroll
      for (int i = 0; i < 2; i++){
        int li = i*256 + tid;
        int row = li >> 2, p = li & 3;
        int sl = p ^ ((row >> 1) & 3);
        gl_lds16(&A1[(size_t)(m0 + row)*512 + k0 + sl*8], &AsB[buf*4096 + (i*256 + wid*64)*8]);
      }
      #pragma unroll
      for (int i = 0; i < 2; i++){
        int li = i*256 + tid;
        int row = li >> 2, p = li & 3;
        int sl = p ^ ((row >> 1) & 3);
        gl_lds16(&wT1[(size_t)(n0 + row)*512 + k0 + sl*8], &BsB[buf*4096 + (i*256 + wid*64)*8]);
      }
    };
    auto compute = [&](int buf){
      bf16x8 af[4], bfr[4];
      #pragma unroll
      for (int mi = 0; mi < 4; mi++){
        int row = wr*64 + mi*16 + ln;
        af[mi] = *(const bf16x8*)&AsB[buf*4096 + row*32 + ((lg ^ ((row >> 1) & 3)) << 3)];
      }
      #pragma unroll
      for (int ni = 0; ni < 4; ni++){
        int row = wc*64 + ni*16 + ln;
        bfr[ni] = *(const bf16x8*)&BsB[buf*4096 + row*32 + ((lg ^ ((row >> 1) & 3)) << 3)];
      }
      #pragma unroll
      for (int mi = 0; mi < 4; mi++)
        #pragma unroll
        for (int ni = 0; ni < 4; ni++)
          acc[mi][ni] = __builtin_amdgcn_mfma_f32_16x16x32_bf16(af[mi], bfr[ni], acc[mi][ni], 0, 0, 0);
    };

    stage(0, 0);
    stage(32, 1);
    #pragma unroll 1
    for (int kt = 0; kt < 16; kt++){
      if (kt < 15) asm volatile("s_waitcnt vmcnt(4)" ::: "memory");
      else         asm volatile("s_waitcnt vmcnt(0)" ::: "memory");
      __builtin_amdgcn_s_barrier();
      __builtin_amdgcn_sched_barrier(0);
      if (kt < 14) stage((kt+2)*32, (kt+2)%3);
      compute(kt%3);
      asm volatile("s_waitcnt lgkmcnt(0)" ::: "memory");
      __builtin_amdgcn_sched_barrier(0);
      __builtin_amdgcn_s_barrier();
    }

    short* Ct = (short*)RAW;
    #pragma unroll
    for (int mi = 0; mi < 4; mi++){
      int mrow = wr*64 + mi*16 + lg*4;
      #pragma unroll
      for (int ni = 0; ni < 4; ni++){
        int ncol = wc*64 + ni*16 + ln;
        #pragma unroll
        for (int r = 0; r < 4; r++)
          Ct[(mrow + r)*136 + ncol] = (short)f2b(acc[mi][ni][r]);
      }
    }
    __syncthreads();
    const int sq = n0 >> 9;
    const int b = m0 >> 11, nseqb = m0 & 2047;
    const int h0 = (n0 & 511) >> 6;
    if (sq < 2){
      short* dstbase = (sq == 0 ? qb : kb);
      #pragma unroll
      for (int c = 0; c < 8; c++){
        int m = c*16 + (tid >> 4);
        int n = (tid & 15) * 8;
        bf16x8 v = *(const bf16x8*)&Ct[m*136 + n];
        int bh = b*8 + h0 + (n >> 6);
        *(bf16x8*)&dstbase[(size_t)bh*131072 + (size_t)(nseqb + m)*64 + (n & 63)] = v;
      }
    } else {
      const int w2 = tid >> 7;
      const int n = tid & 127;
      const int bh = b*8 + h0 + (n >> 6);
      const int d = n & 63;
      #pragma unroll
      for (int c = 0; c < 8; c++){
        int mb = w2*64 + c*8;
        short t0 = Ct[(mb+0)*136 + n], t1 = Ct[(mb+1)*136 + n];
        short t2 = Ct[(mb+2)*136 + n], t3 = Ct[(mb+3)*136 + n];
        short t4 = Ct[(mb+4)*136 + n], t5 = Ct[(mb+5)*136 + n];
        short t6 = Ct[(mb+6)*136 + n], t7 = Ct[(mb+7)*136 + n];
        bf16x8 v = {t0, t1, t2, t3, t4, t5, t6, t7};
        *(bf16x8*)&vT[(size_t)bh*131072 + (size_t)d*2048 + (nseqb + mb)] = v;
      }
      {
        int gl = tid >> 7, nn = tid & 127;
        int mrel = gl*64;
        int bh2 = b*8 + h0 + (nn >> 6);
        int d2 = nn & 63;
        vgT[(size_t)bh2*2048 + d2*32 + ((nseqb + mrel) >> 6)] = Ct[mrel*136 + nn];
      }
    }
  }
  grid_barrier(&bar[0], 512);

  // ---------------- phase 2: attention (512 blocks; R10 body) ----------------
  {
    short (*Ps)[16][168] = (short (*)[16][168])RAW;
    const int s = (bid & 7)*64 + (bid >> 3);            // XCD swizzle
    const int qt = s & 31, bh = s >> 5;
    const int qbase = qt * 64;
    const int w = wid;
    const size_t base = (size_t)bh * (N_SEQ * DH);
    const short* Qp = qb + base;
    const short* Kp = kb + base;
    const short* Vt = vT + base;
    const short* Vg = vgT + (size_t)bh * (DH * 32);
    const int i = qbase + w*16 + ln;
    const int kwin0 = qbase - 64;

    bf16x8 qf[2];
    #pragma unroll
    for (int ks = 0; ks < 2; ks++)
      qf[ks] = *(const bf16x8*)&Qp[(size_t)i*DH + ks*32 + lg*8];

    f32x4 sL[8], sG[2];
    #pragma unroll
    for (int f = 0; f < 8; f++){ f32x4 z = {0.f,0.f,0.f,0.f}; sL[f] = z; }
    #pragma unroll
    for (int f = 0; f < 2; f++){ f32x4 z = {0.f,0.f,0.f,0.f}; sG[f] = z; }
    #pragma unroll
    for (int f = 0; f < 8; f++){
      const short* kr = Kp + (long long)(kwin0 + f*16 + ln) * DH;
      #pragma unroll
      for (int ks = 0; ks < 2; ks++){
        bf16x8 kf = *(const bf16x8*)&kr[ks*32 + lg*8];
        sL[f] = __builtin_amdgcn_mfma_f32_16x16x32_bf16(kf, qf[ks], sL[f], 0, 0, 0);
      }
    }
    #pragma unroll
    for (int fg = 0; fg < 2; fg++){
      const short* kr = Kp + (size_t)(fg*16 + ln) * (WINDOW * DH);
      #pragma unroll
      for (int ks = 0; ks < 2; ks++){
        bf16x8 kf = *(const bf16x8*)&kr[ks*32 + lg*8];
        sG[fg] = __builtin_amdgcn_mfma_f32_16x16x32_bf16(kf, qf[ks], sG[fg], 0, 0, 0);
      }
    }

    float mx = -1e30f;
    #pragma unroll
    for (int f = 0; f < 8; f++){
      #pragma unroll
      for (int r = 0; r < 4; r++){
        int j = kwin0 + 16*f + lg*4 + r;
        bool valid = (j >= 0) && (j <= i) && (i - j <= WINDOW);
        float sv = valid ? sL[f][r] * 0.125f : -1e30f;
        sL[f][r] = sv;
        mx = fmaxf(mx, sv);
      }
    }
    mx = fmaxf(mx, __shfl_xor(mx, 16));
    mx = fmaxf(mx, __shfl_xor(mx, 32));
    float sum = 0.f;
    #pragma unroll
    for (int f = 0; f < 8; f++){
      #pragma unroll
      for (int r = 0; r < 4; r++){
        float p = __expf(sL[f][r] - mx);
        sL[f][r] = p;
        sum += p;
      }
    }
    sum += __shfl_xor(sum, 16);
    sum += __shfl_xor(sum, 32);
    float inv = 1.f / sum;
    #pragma unroll
    for (int f = 0; f < 8; f++){
      short4v pk;
      #pragma unroll
      for (int r = 0; r < 4; r++) pk[r] = (short)f2b(sL[f][r] * inv);
      *(short4v*)&Ps[w][ln][16*f + 4*lg] = pk;
    }
    float mg = -1e30f;
    #pragma unroll
    for (int fg = 0; fg < 2; fg++)
      #pragma unroll
      for (int r = 0; r < 4; r++){
        float sv = sG[fg][r] * 0.125f;
        sG[fg][r] = sv;
        mg = fmaxf(mg, sv);
      }
    mg = fmaxf(mg, __shfl_xor(mg, 16));
    mg = fmaxf(mg, __shfl_xor(mg, 32));
    float sg2 = 0.f;
    #pragma unroll
    for (int fg = 0; fg < 2; fg++)
      #pragma unroll
      for (int r = 0; r < 4; r++){
        float p = __expf(sG[fg][r] - mg);
        sG[fg][r] = p;
        sg2 += p;
      }
    sg2 += __shfl_xor(sg2, 16);
    sg2 += __shfl_xor(sg2, 32);
    float invg = 1.f / sg2;
    #pragma unroll
    for (int fg = 0; fg < 2; fg++){
      short4v pk;
      #pragma unroll
      for (int r = 0; r < 4; r++) pk[r] = (short)f2b(sG[fg][r] * invg);
      *(short4v*)&Ps[w][ln][128 + 16*fg + 4*lg] = pk;
    }
    __syncthreads();

    bf16x8 pa[5];
    #pragma unroll
    for (int ks = 0; ks < 5; ks++)
      pa[ks] = *(const bf16x8*)&Ps[w][ln][ks*32 + lg*8];
    f32x4 o[4];
    #pragma unroll
    for (int n16 = 0; n16 < 4; n16++){ f32x4 z = {0.f,0.f,0.f,0.f}; o[n16] = z; }
    #pragma unroll
    for (int n16 = 0; n16 < 4; n16++){
      int d = n16*16 + ln;
      #pragma unroll
      for (int ks = 0; ks < 4; ks++){
        bf16x8 vv = *(const bf16x8*)&Vt[(long long)d*N_SEQ + kwin0 + ks*32 + lg*8];
        o[n16] = __builtin_amdgcn_mfma_f32_16x16x32_bf16(pa[ks], vv, o[n16], 0, 0, 0);
      }
      bf16x8 vv = *(const bf16x8*)&Vg[d*32 + lg*8];
      o[n16] = __builtin_amdgcn_mfma_f32_16x16x32_bf16(pa[4], vv, o[n16], 0, 0, 0);
    }

    const int h = bh & 7, b = bh >> 3;
    #pragma unroll
    for (int n16 = 0; n16 < 4; n16++){
      int d = n16*16 + ln;
      #pragma unroll
      for (int r = 0; r < 4; r++){
        int qrow = qbase + 16*w + lg*4 + r;
        A2[(size_t)(b*N_SEQ + qrow)*CDIM + h*DH + d] = (short)f2b(o[n16][r]);
      }
    }
  }
  grid_barrier(&bar[1], 512);

  // ---------------- phase 3: out GEMM (256 of 512 blocks; R10 body) ----------------
  if (bid < 256){
    short* AsB = (short*)RAW;                       // 3 x 2048 shorts
    short* BsB = (short*)RAW + 3*2048;              // 3 x 4096 shorts
    const int s = (bid & 7)*32 + (bid >> 3);        // XCD swizzle
    const int m0 = (s >> 2)*64, n0 = (s & 3)*128;
    const int wr = wid >> 1, wc = wid & 1;          // FM=2, FN=4
    f32x4 acc[2][4];
    #pragma unroll
    for (int mi = 0; mi < 2; mi++)
      #pragma unroll
      for (int ni = 0; ni < 4; ni++){ f32x4 z = {0.f,0.f,0.f,0.f}; acc[mi][ni] = z; }

    auto stage = [&](int k0, int buf){
      {
        int row = tid >> 2, p = tid & 3;
        int sl = p ^ ((row >> 1) & 3);
        gl_lds16(&A2[(size_t)(m0 + row)*CDIM + k0 + sl*8], &AsB[buf*2048 + (wid*64)*8]);
      }
      #pragma unroll
      for (int i = 0; i < 2; i++){
        int li = i*256 + tid;
        int row = li >> 2, p = li & 3;
        int sl = p ^ ((row >> 1) & 3);
        gl_lds16(&wT2[(size_t)(n0 + row)*CDIM + k0 + sl*8], &BsB[buf*4096 + (i*256 + wid*64)*8]);
      }
    };
    auto compute = [&](int buf){
      bf16x8 af[2], bfr[4];
      #pragma unroll
      for (int mi = 0; mi < 2; mi++){
        int row = wr*32 + mi*16 + ln;
        af[mi] = *(const bf16x8*)&AsB[buf*2048 + row*32 + ((lg ^ ((row >> 1) & 3)) << 3)];
      }
      #pragma unroll
      for (int ni = 0; ni < 4; ni++){
        int row = wc*64 + ni*16 + ln;
        bfr[ni] = *(const bf16x8*)&BsB[buf*4096 + row*32 + ((lg ^ ((row >> 1) & 3)) << 3)];
      }
      #pragma unroll
      for (int mi = 0; mi < 2; mi++)
        #pragma unroll
        for (int ni = 0; ni < 4; ni++)
          acc[mi][ni] = __builtin_amdgcn_mfma_f32_16x16x32_bf16(af[mi], bfr[ni], acc[mi][ni], 0, 0, 0);
    };

    stage(0, 0);
    stage(32, 1);
    #pragma unroll 1
    for (int kt = 0; kt < 16; kt++){
      if (kt < 15) asm volatile("s_waitcnt vmcnt(3)" ::: "memory");
      else         asm volatile("s_waitcnt vmcnt(0)" ::: "memory");
      __builtin_amdgcn_s_barrier();
      __builtin_amdgcn_sched_barrier(0);
      if (kt < 14) stage((kt+2)*32, (kt+2)%3);
      compute(kt%3);
      asm volatile("s_waitcnt lgkmcnt(0)" ::: "memory");
      __builtin_amdgcn_sched_barrier(0);
      __builtin_amdgcn_s_barrier();
    }

    #pragma unroll
    for (int mi = 0; mi < 2; mi++){
      int mbase = m0 + wr*32 + mi*16 + lg*4;
      #pragma unroll
      for (int ni = 0; ni < 4; ni++){
        int jg = n0 + wc*64 + ni*16 + ln;
        float bi = bias[jg];
        #pragma unroll
        for (int r = 0; r < 4; r++)
          outp[(size_t)(mbase + r)*CDIM + jg] = acc[mi][ni][r] + bi;
      }
    }
  }
}

extern "C" void kernel_launch(void* const* d_in, const int* in_sizes, int n_in,
                              void* d_out, int out_size, void* d_ws, size_t ws_size,
                              hipStream_t stream){
  const float* x      = (const float*)d_in[0];
  const float* w_qkv  = (const float*)d_in[1];
  const float* lA_qkv = (const float*)d_in[2];
  const float* lB_qkv = (const float*)d_in[3];
  const float* w_out  = (const float*)d_in[4];
  const float* b_out  = (const float*)d_in[5];
  const float* lA_out = (const float*)d_in[6];
  const float* lB_out = (const float*)d_in[7];
  float* out = (float*)d_out;

  short* A1  = (short*)d_ws;                       // [4096][512]
  short* wT1 = A1  + (size_t)4096*512;             // [1536][512]  (W_eff^T)
  short* wT2 = wT1 + (size_t)1536*512;             // [512][512]   (W_eff^T)
  short* qb  = wT2 + (size_t)512*512;              // [16][2048][64]
  short* kb  = qb  + (size_t)16*2048*64;
  short* vT  = kb  + (size_t)16*2048*64;           // [16][64][2048]
  short* vgT = vT  + (size_t)16*2048*64;           // [16][64][32]
  short* A2  = vgT + (size_t)16*64*32;             // [4096][512]
  unsigned* bar = (unsigned*)(A2 + (size_t)4096*512);  // 8 counters

  prep<<<768, 256, 0, stream>>>(x, w_qkv, lA_qkv, lB_qkv, w_out, lA_out, lB_out,
                                A1, wT1, wT2, bar);
  mega<<<512, 256, 0, stream>>>(A1, wT1, wT2, b_out, qb, kb, vT, vgT, A2, out, bar);
}

// Round 13
// 181.742 us; speedup vs baseline: 2.0477x; 2.0477x over previous
//
#include <hip/hip_runtime.h>

#define N_SEQ 2048
#define CDIM 512
#define HEADS 8
#define DH 64
#define WINDOW 64
#define BATCH 2

typedef __attribute__((ext_vector_type(8))) short bf16x8;
typedef __attribute__((ext_vector_type(4))) short short4v;
typedef __attribute__((ext_vector_type(4))) float f32x4;

__device__ __forceinline__ unsigned short f2b(float f){
  unsigned u = __float_as_uint(f);
  unsigned r = (u + 0x7fffu + ((u >> 16) & 1u)) >> 16;
  return (unsigned short)r;
}
__device__ __forceinline__ float b2f(unsigned short h){ return __uint_as_float(((unsigned)h) << 16); }

__device__ __forceinline__ void gl_lds16(const void* g, void* l){
  __builtin_amdgcn_global_load_lds(
      (const __attribute__((address_space(1))) void*)g,
      (__attribute__((address_space(3))) void*)l, 16, 0, 0);
}

// grid-wide barrier, flag-based: thread0-only atomics (1 wbl2/inv per BLOCK, not per thread);
// spinners poll a separate flag line (no RMW contention) with sleep backoff.
// All 512 blocks resident by construction (launch_bounds(256,2) -> 2 blocks/CU, 256 CUs).
__device__ __forceinline__ void grid_barrier(unsigned* cnt, unsigned* flag, unsigned nblocks){
  __syncthreads();                                   // drains vmcnt: block's stores are in (local) L2
  if (threadIdx.x == 0){
    unsigned old = __hip_atomic_fetch_add(cnt, 1u, __ATOMIC_ACQ_REL, __HIP_MEMORY_SCOPE_AGENT);
    if (old == nblocks - 1){
      __hip_atomic_store(flag, 1u, __ATOMIC_RELEASE, __HIP_MEMORY_SCOPE_AGENT);
    } else {
      while (!__hip_atomic_load(flag, __ATOMIC_ACQUIRE, __HIP_MEMORY_SCOPE_AGENT))
        __builtin_amdgcn_s_sleep(64);
    }
  }
  __syncthreads();
}

// ================= prep: x->bf16 + fused-weight transposes (W_eff = w + 0.25*lA@lB)
//                   + zero the mega-kernel barrier words =================
__global__ __launch_bounds__(256) void prep(
    const float* __restrict__ x,
    const float* __restrict__ w_qkv, const float* __restrict__ lA_qkv, const float* __restrict__ lB_qkv,
    const float* __restrict__ w_out, const float* __restrict__ lA_out, const float* __restrict__ lB_out,
    short* __restrict__ A1, short* __restrict__ wT1, short* __restrict__ wT2,
    unsigned* __restrict__ bar){
  const int bx = blockIdx.x, tid = threadIdx.x;
  if (bx < 512){
    #pragma unroll
    for (int j = 0; j < 4; j++){
      int g = bx*1024 + j*256 + tid;          // float4 index over 2M elements
      float4 v = ((const float4*)x)[g];
      short4v pk;
      pk[0] = (short)f2b(v.x); pk[1] = (short)f2b(v.y);
      pk[2] = (short)f2b(v.z); pk[3] = (short)f2b(v.w);
      ((short4v*)A1)[g] = pk;
    }
    return;
  }
  if (bx == 767 && tid < 8) bar[tid] = 0;     // zero barrier counters+flags for mega
  __shared__ float T[64][65];
  __shared__ float lAs[64][9];
  __shared__ float lBs[8][64];
  const float *wsrc, *lA, *lB; short* dst; int NN, ct, kt;
  if (bx < 704){ int bxx = bx - 512; wsrc = w_qkv; lA = lA_qkv; lB = lB_qkv; dst = wT1; NN = 1536; ct = bxx % 24; kt = bxx / 24; }
  else         { int bxx = bx - 704; wsrc = w_out; lA = lA_out; lB = lB_out; dst = wT2; NN = 512;  ct = bxx % 8;  kt = bxx / 8; }
  const int n0 = ct*64, k0 = kt*64;
  {
    int t0 = tid, t1 = tid + 256;
    lAs[t0 >> 3][t0 & 7] = lA[(size_t)(k0 + (t0 >> 3))*8 + (t0 & 7)];
    lAs[t1 >> 3][t1 & 7] = lA[(size_t)(k0 + (t1 >> 3))*8 + (t1 & 7)];
    lBs[t0 >> 6][t0 & 63] = lB[(size_t)(t0 >> 6)*NN + n0 + (t0 & 63)];
    lBs[4 + (t0 >> 6)][t0 & 63] = lB[(size_t)(4 + (t0 >> 6))*NN + n0 + (t0 & 63)];
  }
  #pragma unroll
  for (int it = 0; it < 16; it++){
    int r = (tid >> 6) + it*4, c = tid & 63;
    T[r][c] = wsrc[(size_t)(k0 + r)*NN + n0 + c];
  }
  __syncthreads();
  #pragma unroll
  for (int it = 0; it < 16; it++){
    int rw = (tid >> 6) + it*4, cw = tid & 63;   // out n = n0+rw, k = k0+cw
    float lora = 0.f;
    #pragma unroll
    for (int r = 0; r < 8; r++) lora += lAs[cw][r] * lBs[r][rw];
    dst[(size_t)(n0 + rw)*512 + k0 + cw] = (short)f2b(T[cw][rw] + 0.25f*lora);
  }
}

// ================= mega: qkv GEMM | attn | out GEMM with 2 grid barriers =================
__global__ void __launch_bounds__(256, 2) mega(
    const short* __restrict__ A1, const short* __restrict__ wT1,
    const short* __restrict__ wT2, const float* __restrict__ bias,
    short* __restrict__ qb, short* __restrict__ kb,
    short* __restrict__ vT, short* __restrict__ vgT,
    short* __restrict__ A2, float* __restrict__ outp,
    unsigned* __restrict__ bar){
  __shared__ __align__(16) char RAW[49152];
  const int tid = threadIdx.x;
  const int bid = blockIdx.x;
  const int wid = tid >> 6, lane = tid & 63;
  const int ln = lane & 15, lg = lane >> 4;

  // ---------------- phase 1: qkv GEMM (384 of 512 blocks; R10 body) ----------------
  if (bid < 384){
    short* AsB = (short*)RAW;
    short* BsB = (short*)RAW + 12288;
    const int s = (bid & 7)*48 + (bid >> 3);            // XCD swizzle (384%8==0)
    const int m0 = (s/12)*128, n0 = (s%12)*128;
    const int wr = wid >> 1, wc = wid & 1;              // FM=FN=4
    f32x4 acc[4][4];
    #pragma unroll
    for (int mi = 0; mi < 4; mi++)
      #pragma unroll
      for (int ni = 0; ni < 4; ni++){ f32x4 z = {0.f,0.f,0.f,0.f}; acc[mi][ni] = z; }

    auto stage = [&](int k0, int buf){
      #pragma unroll
      for (int i = 0; i < 2; i++){
        int li = i*256 + tid;
        int row = li >> 2, p = li & 3;
        int sl = p ^ ((row >> 1) & 3);
        gl_lds16(&A1[(size_t)(m0 + row)*512 + k0 + sl*8], &AsB[buf*4096 + (i*256 + wid*64)*8]);
      }
      #pragma unroll
      for (int i = 0; i < 2; i++){
        int li = i*256 + tid;
        int row = li >> 2, p = li & 3;
        int sl = p ^ ((row >> 1) & 3);
        gl_lds16(&wT1[(size_t)(n0 + row)*512 + k0 + sl*8], &BsB[buf*4096 + (i*256 + wid*64)*8]);
      }
    };
    auto compute = [&](int buf){
      bf16x8 af[4], bfr[4];
      #pragma unroll
      for (int mi = 0; mi < 4; mi++){
        int row = wr*64 + mi*16 + ln;
        af[mi] = *(const bf16x8*)&AsB[buf*4096 + row*32 + ((lg ^ ((row >> 1) & 3)) << 3)];
      }
      #pragma unroll
      for (int ni = 0; ni < 4; ni++){
        int row = wc*64 + ni*16 + ln;
        bfr[ni] = *(const bf16x8*)&BsB[buf*4096 + row*32 + ((lg ^ ((row >> 1) & 3)) << 3)];
      }
      #pragma unroll
      for (int mi = 0; mi < 4; mi++)
        #pragma unroll
        for (int ni = 0; ni < 4; ni++)
          acc[mi][ni] = __builtin_amdgcn_mfma_f32_16x16x32_bf16(af[mi], bfr[ni], acc[mi][ni], 0, 0, 0);
    };

    stage(0, 0);
    stage(32, 1);
    #pragma unroll 1
    for (int kt = 0; kt < 16; kt++){
      if (kt < 15) asm volatile("s_waitcnt vmcnt(4)" ::: "memory");
      else         asm volatile("s_waitcnt vmcnt(0)" ::: "memory");
      __builtin_amdgcn_s_barrier();
      __builtin_amdgcn_sched_barrier(0);
      if (kt < 14) stage((kt+2)*32, (kt+2)%3);
      compute(kt%3);
      asm volatile("s_waitcnt lgkmcnt(0)" ::: "memory");
      __builtin_amdgcn_sched_barrier(0);
      __builtin_amdgcn_s_barrier();
    }

    short* Ct = (short*)RAW;
    #pragma unroll
    for (int mi = 0; mi < 4; mi++){
      int mrow = wr*64 + mi*16 + lg*4;
      #pragma unroll
      for (int ni = 0; ni < 4; ni++){
        int ncol = wc*64 + ni*16 + ln;
        #pragma unroll
        for (int r = 0; r < 4; r++)
          Ct[(mrow + r)*136 + ncol] = (short)f2b(acc[mi][ni][r]);
      }
    }
    __syncthreads();
    const int sq = n0 >> 9;
    const int b = m0 >> 11, nseqb = m0 & 2047;
    const int h0 = (n0 & 511) >> 6;
    if (sq < 2){
      short* dstbase = (sq == 0 ? qb : kb);
      #pragma unroll
      for (int c = 0; c < 8; c++){
        int m = c*16 + (tid >> 4);
        int n = (tid & 15) * 8;
        bf16x8 v = *(const bf16x8*)&Ct[m*136 + n];
        int bh = b*8 + h0 + (n >> 6);
        *(bf16x8*)&dstbase[(size_t)bh*131072 + (size_t)(nseqb + m)*64 + (n & 63)] = v;
      }
    } else {
      const int w2 = tid >> 7;
      const int n = tid & 127;
      const int bh = b*8 + h0 + (n >> 6);
      const int d = n & 63;
      #pragma unroll
      for (int c = 0; c < 8; c++){
        int mb = w2*64 + c*8;
        short t0 = Ct[(mb+0)*136 + n], t1 = Ct[(mb+1)*136 + n];
        short t2 = Ct[(mb+2)*136 + n], t3 = Ct[(mb+3)*136 + n];
        short t4 = Ct[(mb+4)*136 + n], t5 = Ct[(mb+5)*136 + n];
        short t6 = Ct[(mb+6)*136 + n], t7 = Ct[(mb+7)*136 + n];
        bf16x8 v = {t0, t1, t2, t3, t4, t5, t6, t7};
        *(bf16x8*)&vT[(size_t)bh*131072 + (size_t)d*2048 + (nseqb + mb)] = v;
      }
      {
        int gl = tid >> 7, nn = tid & 127;
        int mrel = gl*64;
        int bh2 = b*8 + h0 + (nn >> 6);
        int d2 = nn & 63;
        vgT[(size_t)bh2*2048 + d2*32 + ((nseqb + mrel) >> 6)] = Ct[mrel*136 + nn];
      }
    }
  }
  grid_barrier(&bar[0], &bar[1], 512);

  // ---------------- phase 2: attention (512 blocks; R10 body) ----------------
  {
    short (*Ps)[16][168] = (short (*)[16][168])RAW;
    const int s = (bid & 7)*64 + (bid >> 3);            // XCD swizzle
    const int qt = s & 31, bh = s >> 5;
    const int qbase = qt * 64;
    const int w = wid;
    const size_t base = (size_t)bh * (N_SEQ * DH);
    const short* Qp = qb + base;
    const short* Kp = kb + base;
    const short* Vt = vT + base;
    const short* Vg = vgT + (size_t)bh * (DH * 32);
    const int i = qbase + w*16 + ln;
    const int kwin0 = qbase - 64;

    bf16x8 qf[2];
    #pragma unroll
    for (int ks = 0; ks < 2; ks++)
      qf[ks] = *(const bf16x8*)&Qp[(size_t)i*DH + ks*32 + lg*8];

    f32x4 sL[8], sG[2];
    #pragma unroll
    for (int f = 0; f < 8; f++){ f32x4 z = {0.f,0.f,0.f,0.f}; sL[f] = z; }
    #pragma unroll
    for (int f = 0; f < 2; f++){ f32x4 z = {0.f,0.f,0.f,0.f}; sG[f] = z; }
    #pragma unroll
    for (int f = 0; f < 8; f++){
      const short* kr = Kp + (long long)(kwin0 + f*16 + ln) * DH;
      #pragma unroll
      for (int ks = 0; ks < 2; ks++){
        bf16x8 kf = *(const bf16x8*)&kr[ks*32 + lg*8];
        sL[f] = __builtin_amdgcn_mfma_f32_16x16x32_bf16(kf, qf[ks], sL[f], 0, 0, 0);
      }
    }
    #pragma unroll
    for (int fg = 0; fg < 2; fg++){
      const short* kr = Kp + (size_t)(fg*16 + ln) * (WINDOW * DH);
      #pragma unroll
      for (int ks = 0; ks < 2; ks++){
        bf16x8 kf = *(const bf16x8*)&kr[ks*32 + lg*8];
        sG[fg] = __builtin_amdgcn_mfma_f32_16x16x32_bf16(kf, qf[ks], sG[fg], 0, 0, 0);
      }
    }

    float mx = -1e30f;
    #pragma unroll
    for (int f = 0; f < 8; f++){
      #pragma unroll
      for (int r = 0; r < 4; r++){
        int j = kwin0 + 16*f + lg*4 + r;
        bool valid = (j >= 0) && (j <= i) && (i - j <= WINDOW);
        float sv = valid ? sL[f][r] * 0.125f : -1e30f;
        sL[f][r] = sv;
        mx = fmaxf(mx, sv);
      }
    }
    mx = fmaxf(mx, __shfl_xor(mx, 16));
    mx = fmaxf(mx, __shfl_xor(mx, 32));
    float sum = 0.f;
    #pragma unroll
    for (int f = 0; f < 8; f++){
      #pragma unroll
      for (int r = 0; r < 4; r++){
        float p = __expf(sL[f][r] - mx);
        sL[f][r] = p;
        sum += p;
      }
    }
    sum += __shfl_xor(sum, 16);
    sum += __shfl_xor(sum, 32);
    float inv = 1.f / sum;
    #pragma unroll
    for (int f = 0; f < 8; f++){
      short4v pk;
      #pragma unroll
      for (int r = 0; r < 4; r++) pk[r] = (short)f2b(sL[f][r] * inv);
      *(short4v*)&Ps[w][ln][16*f + 4*lg] = pk;
    }
    float mg = -1e30f;
    #pragma unroll
    for (int fg = 0; fg < 2; fg++)
      #pragma unroll
      for (int r = 0; r < 4; r++){
        float sv = sG[fg][r] * 0.125f;
        sG[fg][r] = sv;
        mg = fmaxf(mg, sv);
      }
    mg = fmaxf(mg, __shfl_xor(mg, 16));
    mg = fmaxf(mg, __shfl_xor(mg, 32));
    float sg2 = 0.f;
    #pragma unroll
    for (int fg = 0; fg < 2; fg++)
      #pragma unroll
      for (int r = 0; r < 4; r++){
        float p = __expf(sG[fg][r] - mg);
        sG[fg][r] = p;
        sg2 += p;
      }
    sg2 += __shfl_xor(sg2, 16);
    sg2 += __shfl_xor(sg2, 32);
    float invg = 1.f / sg2;
    #pragma unroll
    for (int fg = 0; fg < 2; fg++){
      short4v pk;
      #pragma unroll
      for (int r = 0; r < 4; r++) pk[r] = (short)f2b(sG[fg][r] * invg);
      *(short4v*)&Ps[w][ln][128 + 16*fg + 4*lg] = pk;
    }
    __syncthreads();

    bf16x8 pa[5];
    #pragma unroll
    for (int ks = 0; ks < 5; ks++)
      pa[ks] = *(const bf16x8*)&Ps[w][ln][ks*32 + lg*8];
    f32x4 o[4];
    #pragma unroll
    for (int n16 = 0; n16 < 4; n16++){ f32x4 z = {0.f,0.f,0.f,0.f}; o[n16] = z; }
    #pragma unroll
    for (int n16 = 0; n16 < 4; n16++){
      int d = n16*16 + ln;
      #pragma unroll
      for (int ks = 0; ks < 4; ks++){
        bf16x8 vv = *(const bf16x8*)&Vt[(long long)d*N_SEQ + kwin0 + ks*32 + lg*8];
        o[n16] = __builtin_amdgcn_mfma_f32_16x16x32_bf16(pa[ks], vv, o[n16], 0, 0, 0);
      }
      bf16x8 vv = *(const bf16x8*)&Vg[d*32 + lg*8];
      o[n16] = __builtin_amdgcn_mfma_f32_16x16x32_bf16(pa[4], vv, o[n16], 0, 0, 0);
    }

    const int h = bh & 7, b = bh >> 3;
    #pragma unroll
    for (int n16 = 0; n16 < 4; n16++){
      int d = n16*16 + ln;
      #pragma unroll
      for (int r = 0; r < 4; r++){
        int qrow = qbase + 16*w + lg*4 + r;
        A2[(size_t)(b*N_SEQ + qrow)*CDIM + h*DH + d] = (short)f2b(o[n16][r]);
      }
    }
  }
  grid_barrier(&bar[2], &bar[3], 512);

  // ---------------- phase 3: out GEMM (256 of 512 blocks; R10 body) ----------------
  if (bid < 256){
    short* AsB = (short*)RAW;                       // 3 x 2048 shorts
    short* BsB = (short*)RAW + 3*2048;              // 3 x 4096 shorts
    const int s = (bid & 7)*32 + (bid >> 3);        // XCD swizzle
    const int m0 = (s >> 2)*64, n0 = (s & 3)*128;
    const int wr = wid >> 1, wc = wid & 1;          // FM=2, FN=4
    f32x4 acc[2][4];
    #pragma unroll
    for (int mi = 0; mi < 2; mi++)
      #pragma unroll
      for (int ni = 0; ni < 4; ni++){ f32x4 z = {0.f,0.f,0.f,0.f}; acc[mi][ni] = z; }

    auto stage = [&](int k0, int buf){
      {
        int row = tid >> 2, p = tid & 3;
        int sl = p ^ ((row >> 1) & 3);
        gl_lds16(&A2[(size_t)(m0 + row)*CDIM + k0 + sl*8], &AsB[buf*2048 + (wid*64)*8]);
      }
      #pragma unroll
      for (int i = 0; i < 2; i++){
        int li = i*256 + tid;
        int row = li >> 2, p = li & 3;
        int sl = p ^ ((row >> 1) & 3);
        gl_lds16(&wT2[(size_t)(n0 + row)*CDIM + k0 + sl*8], &BsB[buf*4096 + (i*256 + wid*64)*8]);
      }
    };
    auto compute = [&](int buf){
      bf16x8 af[2], bfr[4];
      #pragma unroll
      for (int mi = 0; mi < 2; mi++){
        int row = wr*32 + mi*16 + ln;
        af[mi] = *(const bf16x8*)&AsB[buf*2048 + row*32 + ((lg ^ ((row >> 1) & 3)) << 3)];
      }
      #pragma unroll
      for (int ni = 0; ni < 4; ni++){
        int row = wc*64 + ni*16 + ln;
        bfr[ni] = *(const bf16x8*)&BsB[buf*4096 + row*32 + ((lg ^ ((row >> 1) & 3)) << 3)];
      }
      #pragma unroll
      for (int mi = 0; mi < 2; mi++)
        #pragma unroll
        for (int ni = 0; ni < 4; ni++)
          acc[mi][ni] = __builtin_amdgcn_mfma_f32_16x16x32_bf16(af[mi], bfr[ni], acc[mi][ni], 0, 0, 0);
    };

    stage(0, 0);
    stage(32, 1);
    #pragma unroll 1
    for (int kt = 0; kt < 16; kt++){
      if (kt < 15) asm volatile("s_waitcnt vmcnt(3)" ::: "memory");
      else         asm volatile("s_waitcnt vmcnt(0)" ::: "memory");
      __builtin_amdgcn_s_barrier();
      __builtin_amdgcn_sched_barrier(0);
      if (kt < 14) stage((kt+2)*32, (kt+2)%3);
      compute(kt%3);
      asm volatile("s_waitcnt lgkmcnt(0)" ::: "memory");
      __builtin_amdgcn_sched_barrier(0);
      __builtin_amdgcn_s_barrier();
    }

    #pragma unroll
    for (int mi = 0; mi < 2; mi++){
      int mbase = m0 + wr*32 + mi*16 + lg*4;
      #pragma unroll
      for (int ni = 0; ni < 4; ni++){
        int jg = n0 + wc*64 + ni*16 + ln;
        float bi = bias[jg];
        #pragma unroll
        for (int r = 0; r < 4; r++)
          outp[(size_t)(mbase + r)*CDIM + jg] = acc[mi][ni][r] + bi;
      }
    }
  }
}

extern "C" void kernel_launch(void* const* d_in, const int* in_sizes, int n_in,
                              void* d_out, int out_size, void* d_ws, size_t ws_size,
                              hipStream_t stream){
  const float* x      = (const float*)d_in[0];
  const float* w_qkv  = (const float*)d_in[1];
  const float* lA_qkv = (const float*)d_in[2];
  const float* lB_qkv = (const float*)d_in[3];
  const float* w_out  = (const float*)d_in[4];
  const float* b_out  = (const float*)d_in[5];
  const float* lA_out = (const float*)d_in[6];
  const float* lB_out = (const float*)d_in[7];
  float* out = (float*)d_out;

  short* A1  = (short*)d_ws;                       // [4096][512]
  short* wT1 = A1  + (size_t)4096*512;             // [1536][512]  (W_eff^T)
  short* wT2 = wT1 + (size_t)1536*512;             // [512][512]   (W_eff^T)
  short* qb  = wT2 + (size_t)512*512;              // [16][2048][64]
  short* kb  = qb  + (size_t)16*2048*64;
  short* vT  = kb  + (size_t)16*2048*64;           // [16][64][2048]
  short* vgT = vT  + (size_t)16*2048*64;           // [16][64][32]
  short* A2  = vgT + (size_t)16*64*32;             // [4096][512]
  unsigned* bar = (unsigned*)(A2 + (size_t)4096*512);  // 8 words: {cnt0,flag0,cnt1,flag1,...}

  prep<<<768, 256, 0, stream>>>(x, w_qkv, lA_qkv, lB_qkv, w_out, lA_out, lB_out,
                                A1, wT1, wT2, bar);
  mega<<<512, 256, 0, stream>>>(A1, wT1, wT2, b_out, qb, kb, vT, vgT, A2, out, bar);
}

// Round 14
// 49.599 us; speedup vs baseline: 7.5034x; 3.6642x over previous
//
#include <hip/hip_runtime.h>

#define N_SEQ 2048
#define CDIM 512
#define HEADS 8
#define DH 64
#define WINDOW 64
#define BATCH 2

typedef __attribute__((ext_vector_type(8))) short bf16x8;
typedef __attribute__((ext_vector_type(4))) short short4v;
typedef __attribute__((ext_vector_type(4))) float f32x4;

__device__ __forceinline__ unsigned short f2b(float f){
  unsigned u = __float_as_uint(f);
  unsigned r = (u + 0x7fffu + ((u >> 16) & 1u)) >> 16;
  return (unsigned short)r;
}
__device__ __forceinline__ float b2f(unsigned short h){ return __uint_as_float(((unsigned)h) << 16); }

__device__ __forceinline__ void gl_lds16(const void* g, void* l){
  __builtin_amdgcn_global_load_lds(
      (const __attribute__((address_space(1))) void*)g,
      (__attribute__((address_space(3))) void*)l, 16, 0, 0);
}

// ================= prep: x->bf16 + fused-weight transposes (W_eff = w + 0.25*lA@lB) ======
__global__ __launch_bounds__(256) void prep(
    const float* __restrict__ x,
    const float* __restrict__ w_qkv, const float* __restrict__ lA_qkv, const float* __restrict__ lB_qkv,
    const float* __restrict__ w_out, const float* __restrict__ lA_out, const float* __restrict__ lB_out,
    short* __restrict__ A1, short* __restrict__ wT1, short* __restrict__ wT2){
  const int bx = blockIdx.x, tid = threadIdx.x;
  if (bx < 512){
    #pragma unroll
    for (int j = 0; j < 4; j++){
      int g = bx*1024 + j*256 + tid;          // float4 index over 2M elements
      float4 v = ((const float4*)x)[g];
      short4v pk;
      pk[0] = (short)f2b(v.x); pk[1] = (short)f2b(v.y);
      pk[2] = (short)f2b(v.z); pk[3] = (short)f2b(v.w);
      ((short4v*)A1)[g] = pk;
    }
    return;
  }
  __shared__ float T[64][65];
  __shared__ float lAs[64][9];
  __shared__ float lBs[8][64];
  const float *wsrc, *lA, *lB; short* dst; int NN, ct, kt;
  if (bx < 704){ int bxx = bx - 512; wsrc = w_qkv; lA = lA_qkv; lB = lB_qkv; dst = wT1; NN = 1536; ct = bxx % 24; kt = bxx / 24; }
  else         { int bxx = bx - 704; wsrc = w_out; lA = lA_out; lB = lB_out; dst = wT2; NN = 512;  ct = bxx % 8;  kt = bxx / 8; }
  const int n0 = ct*64, k0 = kt*64;
  {
    int t0 = tid, t1 = tid + 256;
    lAs[t0 >> 3][t0 & 7] = lA[(size_t)(k0 + (t0 >> 3))*8 + (t0 & 7)];
    lAs[t1 >> 3][t1 & 7] = lA[(size_t)(k0 + (t1 >> 3))*8 + (t1 & 7)];
    lBs[t0 >> 6][t0 & 63] = lB[(size_t)(t0 >> 6)*NN + n0 + (t0 & 63)];
    lBs[4 + (t0 >> 6)][t0 & 63] = lB[(size_t)(4 + (t0 >> 6))*NN + n0 + (t0 & 63)];
  }
  #pragma unroll
  for (int it = 0; it < 16; it++){
    int r = (tid >> 6) + it*4, c = tid & 63;
    T[r][c] = wsrc[(size_t)(k0 + r)*NN + n0 + c];
  }
  __syncthreads();
  #pragma unroll
  for (int it = 0; it < 16; it++){
    int rw = (tid >> 6) + it*4, cw = tid & 63;   // out n = n0+rw, k = k0+cw
    float lora = 0.f;
    #pragma unroll
    for (int r = 0; r < 8; r++) lora += lAs[cw][r] * lBs[r][rw];
    dst[(size_t)(n0 + rw)*512 + k0 + cw] = (short)f2b(T[cw][rw] + 0.25f*lora);
  }
}

// ================= qkv GEMM: K=512, 128x128, counted-vmcnt 3-buffer pipeline,
//                   coalesced epilogue via LDS C-tile =================
__global__ __launch_bounds__(256) void gemm_qkv(const short* __restrict__ A,
    const short* __restrict__ Bt,
    short* __restrict__ qb, short* __restrict__ kb,
    short* __restrict__ vT, short* __restrict__ vgT){
  __shared__ __align__(16) short SMEM[24576];          // 48 KB: 3xAs(8KB) + 3xBs(8KB); reused as Ct
  short* AsB = SMEM;
  short* BsB = SMEM + 12288;
  const int tid = threadIdx.x;
  const int wid = tid >> 6, lane = tid & 63;
  const int ln = lane & 15, lg = lane >> 4;
  const int phys = blockIdx.y*12 + blockIdx.x;          // 384 blocks
  const int s = (phys & 7)*48 + (phys >> 3);            // XCD swizzle (384%8==0)
  const int m0 = (s/12)*128, n0 = (s%12)*128;
  const int wr = wid >> 1, wc = wid & 1;                // FM=FN=4, NWC=2
  f32x4 acc[4][4];
  #pragma unroll
  for (int mi = 0; mi < 4; mi++)
    #pragma unroll
    for (int ni = 0; ni < 4; ni++){ f32x4 z = {0.f,0.f,0.f,0.f}; acc[mi][ni] = z; }

  auto stage = [&](int k0, int buf){
    #pragma unroll
    for (int i = 0; i < 2; i++){
      int li = i*256 + tid;
      int row = li >> 2, p = li & 3;
      int sl = p ^ ((row >> 1) & 3);
      gl_lds16(&A[(size_t)(m0 + row)*512 + k0 + sl*8], &AsB[buf*4096 + (i*256 + wid*64)*8]);
    }
    #pragma unroll
    for (int i = 0; i < 2; i++){
      int li = i*256 + tid;
      int row = li >> 2, p = li & 3;
      int sl = p ^ ((row >> 1) & 3);
      gl_lds16(&Bt[(size_t)(n0 + row)*512 + k0 + sl*8], &BsB[buf*4096 + (i*256 + wid*64)*8]);
    }
  };
  auto compute = [&](int buf){
    bf16x8 af[4], bfr[4];
    #pragma unroll
    for (int mi = 0; mi < 4; mi++){
      int row = wr*64 + mi*16 + ln;
      af[mi] = *(const bf16x8*)&AsB[buf*4096 + row*32 + ((lg ^ ((row >> 1) & 3)) << 3)];
    }
    #pragma unroll
    for (int ni = 0; ni < 4; ni++){
      int row = wc*64 + ni*16 + ln;
      bfr[ni] = *(const bf16x8*)&BsB[buf*4096 + row*32 + ((lg ^ ((row >> 1) & 3)) << 3)];
    }
    #pragma unroll
    for (int mi = 0; mi < 4; mi++)
      #pragma unroll
      for (int ni = 0; ni < 4; ni++)
        acc[mi][ni] = __builtin_amdgcn_mfma_f32_16x16x32_bf16(af[mi], bfr[ni], acc[mi][ni], 0, 0, 0);
  };

  stage(0, 0);
  stage(32, 1);
  #pragma unroll 1
  for (int kt = 0; kt < 16; kt++){
    if (kt < 15) asm volatile("s_waitcnt vmcnt(4)" ::: "memory");
    else         asm volatile("s_waitcnt vmcnt(0)" ::: "memory");
    __builtin_amdgcn_s_barrier();
    __builtin_amdgcn_sched_barrier(0);
    if (kt < 14) stage((kt+2)*32, (kt+2)%3);
    compute(kt%3);
    asm volatile("s_waitcnt lgkmcnt(0)" ::: "memory");
    __builtin_amdgcn_sched_barrier(0);
    __builtin_amdgcn_s_barrier();
  }

  // ---- epilogue: acc -> LDS Ct[128][136] -> coalesced 16B global stores ----
  short* Ct = SMEM;
  #pragma unroll
  for (int mi = 0; mi < 4; mi++){
    int mrow = wr*64 + mi*16 + lg*4;
    #pragma unroll
    for (int ni = 0; ni < 4; ni++){
      int ncol = wc*64 + ni*16 + ln;
      #pragma unroll
      for (int r = 0; r < 4; r++)
        Ct[(mrow + r)*136 + ncol] = (short)f2b(acc[mi][ni][r]);
    }
  }
  __syncthreads();
  const int sq = n0 >> 9;
  const int b = m0 >> 11, nseqb = m0 & 2047;
  const int h0 = (n0 & 511) >> 6;
  if (sq < 2){
    short* dstbase = (sq == 0 ? qb : kb);
    #pragma unroll
    for (int c = 0; c < 8; c++){
      int m = c*16 + (tid >> 4);
      int n = (tid & 15) * 8;
      bf16x8 v = *(const bf16x8*)&Ct[m*136 + n];
      int bh = b*8 + h0 + (n >> 6);
      *(bf16x8*)&dstbase[(size_t)bh*131072 + (size_t)(nseqb + m)*64 + (n & 63)] = v;
    }
  } else {
    const int w2 = tid >> 7;
    const int n = tid & 127;
    const int bh = b*8 + h0 + (n >> 6);
    const int d = n & 63;
    #pragma unroll
    for (int c = 0; c < 8; c++){
      int mb = w2*64 + c*8;
      short t0 = Ct[(mb+0)*136 + n], t1 = Ct[(mb+1)*136 + n];
      short t2 = Ct[(mb+2)*136 + n], t3 = Ct[(mb+3)*136 + n];
      short t4 = Ct[(mb+4)*136 + n], t5 = Ct[(mb+5)*136 + n];
      short t6 = Ct[(mb+6)*136 + n], t7 = Ct[(mb+7)*136 + n];
      bf16x8 v = {t0, t1, t2, t3, t4, t5, t6, t7};
      *(bf16x8*)&vT[(size_t)bh*131072 + (size_t)d*2048 + (nseqb + mb)] = v;
    }
    {
      int gl = tid >> 7, nn = tid & 127;
      int mrel = gl*64;
      int bh2 = b*8 + h0 + (nn >> 6);
      int d2 = nn & 63;
      vgT[(size_t)bh2*2048 + d2*32 + ((nseqb + mrel) >> 6)] = Ct[mrel*136 + nn];
    }
  }
}

// ================= fused attention (MFMA) =================
__global__ __launch_bounds__(256) void attn_mfma(const short* __restrict__ qb,
    const short* __restrict__ kb, const short* __restrict__ vT,
    const short* __restrict__ vgT, short* __restrict__ A2){
  __shared__ __align__(16) short Ps[4][16][168];
  const int phys = blockIdx.y*32 + blockIdx.x;          // 512 blocks
  const int s = (phys & 7)*64 + (phys >> 3);            // XCD swizzle
  const int qt = s & 31, bh = s >> 5;
  const int qbase = qt * 64;
  const int tid = threadIdx.x, w = tid >> 6, lane = tid & 63;
  const int ln = lane & 15, lg = lane >> 4;
  const size_t base = (size_t)bh * (N_SEQ * DH);
  const short* Qp = qb + base;
  const short* Kp = kb + base;
  const short* Vt = vT + base;
  const short* Vg = vgT + (size_t)bh * (DH * 32);
  const int i = qbase + w*16 + ln;
  const int kwin0 = qbase - 64;

  bf16x8 qf[2];
  #pragma unroll
  for (int ks = 0; ks < 2; ks++)
    qf[ks] = *(const bf16x8*)&Qp[(size_t)i*DH + ks*32 + lg*8];

  f32x4 sL[8], sG[2];
  #pragma unroll
  for (int f = 0; f < 8; f++){ f32x4 z = {0.f,0.f,0.f,0.f}; sL[f] = z; }
  #pragma unroll
  for (int f = 0; f < 2; f++){ f32x4 z = {0.f,0.f,0.f,0.f}; sG[f] = z; }
  #pragma unroll
  for (int f = 0; f < 8; f++){
    const short* kr = Kp + (long long)(kwin0 + f*16 + ln) * DH;
    #pragma unroll
    for (int ks = 0; ks < 2; ks++){
      bf16x8 kf = *(const bf16x8*)&kr[ks*32 + lg*8];
      sL[f] = __builtin_amdgcn_mfma_f32_16x16x32_bf16(kf, qf[ks], sL[f], 0, 0, 0);
    }
  }
  #pragma unroll
  for (int fg = 0; fg < 2; fg++){
    const short* kr = Kp + (size_t)(fg*16 + ln) * (WINDOW * DH);
    #pragma unroll
    for (int ks = 0; ks < 2; ks++){
      bf16x8 kf = *(const bf16x8*)&kr[ks*32 + lg*8];
      sG[fg] = __builtin_amdgcn_mfma_f32_16x16x32_bf16(kf, qf[ks], sG[fg], 0, 0, 0);
    }
  }

  float mx = -1e30f;
  #pragma unroll
  for (int f = 0; f < 8; f++){
    #pragma unroll
    for (int r = 0; r < 4; r++){
      int j = kwin0 + 16*f + lg*4 + r;
      bool valid = (j >= 0) && (j <= i) && (i - j <= WINDOW);
      float sv = valid ? sL[f][r] * 0.125f : -1e30f;
      sL[f][r] = sv;
      mx = fmaxf(mx, sv);
    }
  }
  mx = fmaxf(mx, __shfl_xor(mx, 16));
  mx = fmaxf(mx, __shfl_xor(mx, 32));
  float sum = 0.f;
  #pragma unroll
  for (int f = 0; f < 8; f++){
    #pragma unroll
    for (int r = 0; r < 4; r++){
      float p = __expf(sL[f][r] - mx);
      sL[f][r] = p;
      sum += p;
    }
  }
  sum += __shfl_xor(sum, 16);
  sum += __shfl_xor(sum, 32);
  float inv = 1.f / sum;
  #pragma unroll
  for (int f = 0; f < 8; f++){
    short4v pk;
    #pragma unroll
    for (int r = 0; r < 4; r++) pk[r] = (short)f2b(sL[f][r] * inv);
    *(short4v*)&Ps[w][ln][16*f + 4*lg] = pk;
  }
  float mg = -1e30f;
  #pragma unroll
  for (int fg = 0; fg < 2; fg++)
    #pragma unroll
    for (int r = 0; r < 4; r++){
      float sv = sG[fg][r] * 0.125f;
      sG[fg][r] = sv;
      mg = fmaxf(mg, sv);
    }
  mg = fmaxf(mg, __shfl_xor(mg, 16));
  mg = fmaxf(mg, __shfl_xor(mg, 32));
  float sg2 = 0.f;
  #pragma unroll
  for (int fg = 0; fg < 2; fg++)
    #pragma unroll
    for (int r = 0; r < 4; r++){
      float p = __expf(sG[fg][r] - mg);
      sG[fg][r] = p;
      sg2 += p;
    }
  sg2 += __shfl_xor(sg2, 16);
  sg2 += __shfl_xor(sg2, 32);
  float invg = 1.f / sg2;
  #pragma unroll
  for (int fg = 0; fg < 2; fg++){
    short4v pk;
    #pragma unroll
    for (int r = 0; r < 4; r++) pk[r] = (short)f2b(sG[fg][r] * invg);
    *(short4v*)&Ps[w][ln][128 + 16*fg + 4*lg] = pk;
  }
  __syncthreads();

  bf16x8 pa[5];
  #pragma unroll
  for (int ks = 0; ks < 5; ks++)
    pa[ks] = *(const bf16x8*)&Ps[w][ln][ks*32 + lg*8];
  f32x4 o[4];
  #pragma unroll
  for (int n16 = 0; n16 < 4; n16++){ f32x4 z = {0.f,0.f,0.f,0.f}; o[n16] = z; }
  #pragma unroll
  for (int n16 = 0; n16 < 4; n16++){
    int d = n16*16 + ln;
    #pragma unroll
    for (int ks = 0; ks < 4; ks++){
      bf16x8 vv = *(const bf16x8*)&Vt[(long long)d*N_SEQ + kwin0 + ks*32 + lg*8];
      o[n16] = __builtin_amdgcn_mfma_f32_16x16x32_bf16(pa[ks], vv, o[n16], 0, 0, 0);
    }
    bf16x8 vv = *(const bf16x8*)&Vg[d*32 + lg*8];
    o[n16] = __builtin_amdgcn_mfma_f32_16x16x32_bf16(pa[4], vv, o[n16], 0, 0, 0);
  }

  const int h = bh & 7, b = bh >> 3;
  #pragma unroll
  for (int n16 = 0; n16 < 4; n16++){
    int d = n16*16 + ln;
    #pragma unroll
    for (int r = 0; r < 4; r++){
      int qrow = qbase + 16*w + lg*4 + r;
      A2[(size_t)(b*N_SEQ + qrow)*CDIM + h*DH + d] = (short)f2b(o[n16][r]);
    }
  }
}

// ================= out GEMM: K=512, 64x128, counted-vmcnt 3-buffer pipeline + bias =====
__global__ __launch_bounds__(256) void gemm_out(const short* __restrict__ A,
    const short* __restrict__ Bt, const float* __restrict__ bias,
    float* __restrict__ outp){
  __shared__ __align__(16) short AsB[3*2048];           // 3 x 64x32
  __shared__ __align__(16) short BsB[3*4096];           // 3 x 128x32
  const int tid = threadIdx.x;
  const int wid = tid >> 6, lane = tid & 63;
  const int ln = lane & 15, lg = lane >> 4;
  const int phys = blockIdx.y*4 + blockIdx.x;           // 256 blocks
  const int s = (phys & 7)*32 + (phys >> 3);            // XCD swizzle
  const int m0 = (s >> 2)*64, n0 = (s & 3)*128;
  const int wr = wid >> 1, wc = wid & 1;                // FM=2, FN=4
  f32x4 acc[2][4];
  #pragma unroll
  for (int mi = 0; mi < 2; mi++)
    #pragma unroll
    for (int ni = 0; ni < 4; ni++){ f32x4 z = {0.f,0.f,0.f,0.f}; acc[mi][ni] = z; }

  auto stage = [&](int k0, int buf){
    {
      int row = tid >> 2, p = tid & 3;
      int sl = p ^ ((row >> 1) & 3);
      gl_lds16(&A[(size_t)(m0 + row)*CDIM + k0 + sl*8], &AsB[buf*2048 + (wid*64)*8]);
    }
    #pragma unroll
    for (int i = 0; i < 2; i++){
      int li = i*256 + tid;
      int row = li >> 2, p = li & 3;
      int sl = p ^ ((row >> 1) & 3);
      gl_lds16(&Bt[(size_t)(n0 + row)*CDIM + k0 + sl*8], &BsB[buf*4096 + (i*256 + wid*64)*8]);
    }
  };
  auto compute = [&](int buf){
    bf16x8 af[2], bfr[4];
    #pragma unroll
    for (int mi = 0; mi < 2; mi++){
      int row = wr*32 + mi*16 + ln;
      af[mi] = *(const bf16x8*)&AsB[buf*2048 + row*32 + ((lg ^ ((row >> 1) & 3)) << 3)];
    }
    #pragma unroll
    for (int ni = 0; ni < 4; ni++){
      int row = wc*64 + ni*16 + ln;
      bfr[ni] = *(const bf16x8*)&BsB[buf*4096 + row*32 + ((lg ^ ((row >> 1) & 3)) << 3)];
    }
    #pragma unroll
    for (int mi = 0; mi < 2; mi++)
      #pragma unroll
      for (int ni = 0; ni < 4; ni++)
        acc[mi][ni] = __builtin_amdgcn_mfma_f32_16x16x32_bf16(af[mi], bfr[ni], acc[mi][ni], 0, 0, 0);
  };

  stage(0, 0);
  stage(32, 1);
  #pragma unroll 1
  for (int kt = 0; kt < 16; kt++){
    if (kt < 15) asm volatile("s_waitcnt vmcnt(3)" ::: "memory");   // tile kt's 3 loads landed
    else         asm volatile("s_waitcnt vmcnt(0)" ::: "memory");
    __builtin_amdgcn_s_barrier();
    __builtin_amdgcn_sched_barrier(0);
    if (kt < 14) stage((kt+2)*32, (kt+2)%3);
    compute(kt%3);
    asm volatile("s_waitcnt lgkmcnt(0)" ::: "memory");
    __builtin_amdgcn_sched_barrier(0);
    __builtin_amdgcn_s_barrier();
  }

  #pragma unroll
  for (int mi = 0; mi < 2; mi++){
    int mbase = m0 + wr*32 + mi*16 + lg*4;
    #pragma unroll
    for (int ni = 0; ni < 4; ni++){
      int jg = n0 + wc*64 + ni*16 + ln;
      float bi = bias[jg];
      #pragma unroll
      for (int r = 0; r < 4; r++)
        outp[(size_t)(mbase + r)*CDIM + jg] = acc[mi][ni][r] + bi;
    }
  }
}

extern "C" void kernel_launch(void* const* d_in, const int* in_sizes, int n_in,
                              void* d_out, int out_size, void* d_ws, size_t ws_size,
                              hipStream_t stream){
  const float* x      = (const float*)d_in[0];
  const float* w_qkv  = (const float*)d_in[1];
  const float* lA_qkv = (const float*)d_in[2];
  const float* lB_qkv = (const float*)d_in[3];
  const float* w_out  = (const float*)d_in[4];
  const float* b_out  = (const float*)d_in[5];
  const float* lA_out = (const float*)d_in[6];
  const float* lB_out = (const float*)d_in[7];
  float* out = (float*)d_out;

  short* A1  = (short*)d_ws;                       // [4096][512]
  short* wT1 = A1  + (size_t)4096*512;             // [1536][512]  (W_eff^T)
  short* wT2 = wT1 + (size_t)1536*512;             // [512][512]   (W_eff^T)
  short* qb  = wT2 + (size_t)512*512;              // [16][2048][64]
  short* kb  = qb  + (size_t)16*2048*64;
  short* vT  = kb  + (size_t)16*2048*64;           // [16][64][2048]
  short* vgT = vT  + (size_t)16*2048*64;           // [16][64][32]
  short* A2  = vgT + (size_t)16*64*32;             // [4096][512]

  prep<<<768, 256, 0, stream>>>(x, w_qkv, lA_qkv, lB_qkv, w_out, lA_out, lB_out,
                                A1, wT1, wT2);
  gemm_qkv<<<dim3(12, 32), 256, 0, stream>>>(A1, wT1, qb, kb, vT, vgT);
  attn_mfma<<<dim3(32, 16), 256, 0, stream>>>(qb, kb, vT, vgT, A2);
  gemm_out<<<dim3(4, 64), 256, 0, stream>>>(A2, wT2, b_out, out);
}